// Round 13
// baseline (83.329 us; speedup 1.0000x reference)
//
#include <hip/hip_runtime.h>

#define BS 8192
#define D  128
#define TI 128              // i-rows per block (2 waves x 64)
#define JCHUNK 512          // j's per block chunk
#define NJC (BS / JCHUNK)   // 16
#define NP 16               // panels per chunk (32 j-rows each)

typedef __bf16 bf16x8 __attribute__((ext_vector_type(8)));
typedef float  f32x16 __attribute__((ext_vector_type(16)));

// ---------------------------------------------------------------------------
// pack: feats -> fragment-major bf16 for BOTH anchor (Apack) and positive
// (Ppack), plus the fp32 row reductions (a_sq, p_sq, pd2). Layout (verified
// R6-R12): piece ((tile*8 + s)*64 + lane) holds the 8 bf16 operand elements
// for MFMA lane `lane` at k-step s of 32-row tile `tile`:
//   row = tile*32 + (lane&31), k = s*16 + (lane>>5)*8 .. +8
// Also zeroes the fin accumulator/ticket (ws is 0xAA-poisoned each launch).
// ---------------------------------------------------------------------------
__global__ __launch_bounds__(256) void pack_kernel(
        const float* __restrict__ feats,
        __bf16* __restrict__ Apack, __bf16* __restrict__ Ppack,
        float* __restrict__ a_sq, float* __restrict__ p_sq,
        float* __restrict__ pd2, float* __restrict__ accum,
        unsigned int* __restrict__ cnt)
{
    const int tile = blockIdx.x;          // 0..255
    const int tid  = threadIdx.x;
    const int r    = tid >> 3;            // row within tile, 0..31
    const int kb   = tid & 7;             // k-block = MFMA step s, 0..7
    const int row  = tile * 32 + r;

    if (tile == 0 && tid == 0) { *accum = 0.0f; *cnt = 0u; }

    const float4* asrc = (const float4*)(feats + (size_t)row * D + kb * 16);
    const float4* psrc = (const float4*)(feats + (size_t)(row + BS) * D + kb * 16);
    float4 a0 = asrc[0], a1 = asrc[1], a2 = asrc[2], a3 = asrc[3];
    float4 p0 = psrc[0], p1 = psrc[1], p2 = psrc[2], p3 = psrc[3];

    bf16x8 alo, ahi, plo, phi;
    alo[0]=(__bf16)a0.x; alo[1]=(__bf16)a0.y; alo[2]=(__bf16)a0.z; alo[3]=(__bf16)a0.w;
    alo[4]=(__bf16)a1.x; alo[5]=(__bf16)a1.y; alo[6]=(__bf16)a1.z; alo[7]=(__bf16)a1.w;
    ahi[0]=(__bf16)a2.x; ahi[1]=(__bf16)a2.y; ahi[2]=(__bf16)a2.z; ahi[3]=(__bf16)a2.w;
    ahi[4]=(__bf16)a3.x; ahi[5]=(__bf16)a3.y; ahi[6]=(__bf16)a3.z; ahi[7]=(__bf16)a3.w;
    plo[0]=(__bf16)p0.x; plo[1]=(__bf16)p0.y; plo[2]=(__bf16)p0.z; plo[3]=(__bf16)p0.w;
    plo[4]=(__bf16)p1.x; plo[5]=(__bf16)p1.y; plo[6]=(__bf16)p1.z; plo[7]=(__bf16)p1.w;
    phi[0]=(__bf16)p2.x; phi[1]=(__bf16)p2.y; phi[2]=(__bf16)p2.z; phi[3]=(__bf16)p2.w;
    phi[4]=(__bf16)p3.x; phi[5]=(__bf16)p3.y; phi[6]=(__bf16)p3.z; phi[7]=(__bf16)p3.w;

    const size_t pb = ((size_t)tile * 8 + kb) * 64;
    ((bf16x8*)Apack)[pb + r]      = alo;
    ((bf16x8*)Apack)[pb + 32 + r] = ahi;
    ((bf16x8*)Ppack)[pb + r]      = plo;
    ((bf16x8*)Ppack)[pb + 32 + r] = phi;

    float sa = a0.x*a0.x + a0.y*a0.y + a0.z*a0.z + a0.w*a0.w
             + a1.x*a1.x + a1.y*a1.y + a1.z*a1.z + a1.w*a1.w
             + a2.x*a2.x + a2.y*a2.y + a2.z*a2.z + a2.w*a2.w
             + a3.x*a3.x + a3.y*a3.y + a3.z*a3.z + a3.w*a3.w;
    float sp = p0.x*p0.x + p0.y*p0.y + p0.z*p0.z + p0.w*p0.w
             + p1.x*p1.x + p1.y*p1.y + p1.z*p1.z + p1.w*p1.w
             + p2.x*p2.x + p2.y*p2.y + p2.z*p2.z + p2.w*p2.w
             + p3.x*p3.x + p3.y*p3.y + p3.z*p3.z + p3.w*p3.w;
    float d;
    float sd = 0.0f;
    d = a0.x-p0.x; sd += d*d;  d = a0.y-p0.y; sd += d*d;
    d = a0.z-p0.z; sd += d*d;  d = a0.w-p0.w; sd += d*d;
    d = a1.x-p1.x; sd += d*d;  d = a1.y-p1.y; sd += d*d;
    d = a1.z-p1.z; sd += d*d;  d = a1.w-p1.w; sd += d*d;
    d = a2.x-p2.x; sd += d*d;  d = a2.y-p2.y; sd += d*d;
    d = a2.z-p2.z; sd += d*d;  d = a2.w-p2.w; sd += d*d;
    d = a3.x-p3.x; sd += d*d;  d = a3.y-p3.y; sd += d*d;
    d = a3.z-p3.z; sd += d*d;  d = a3.w-p3.w; sd += d*d;

    #pragma unroll
    for (int off = 1; off <= 4; off <<= 1) {
        sa += __shfl_xor(sa, off, 64);
        sp += __shfl_xor(sp, off, 64);
        sd += __shfl_xor(sd, off, 64);
    }
    if (kb == 0) { a_sq[row] = sa; p_sq[row] = sp; pd2[row] = sd; }
}

// ---------------------------------------------------------------------------
// max kernel: NO LDS, NO BARRIERS — registers-only B pipeline (R12), with:
//  * #pragma unroll 2 on the panel loop: bounds the scheduler's load hoisting
//    so the footprint stays ~212 VGPR < 256 and (128,2) residency (8 waves/CU)
//    actually holds. (Suspicion: R12's full unroll ballooned VGPRs past 256
//    -> 4 waves/CU -> the persistent ~25 us.)
//  * XCD swizzle: flat bid -> jc = bid & 15. Round-robin XCD dispatch then
//    gives each XCD only ~2 distinct j-chunks (256 KB of B) + Apack, all
//    L2-resident per XCD.
// Each wave owns 64 i-rows (two A-fragment sets register-resident). B panels
// (32 j-rows) double-buffer in registers; panel t+1's 8 coalesced 1 KB loads
// issue before panel t's MFMAs (exact per-register vmcnt tracking).
//
// acc initialized to -p_sq[col]/2, so after the K-loop acc = cross - p_sq/2
// and min_j d2 = a_sq - 2*max acc -> one v_max per reg.
//
// mfma_f32_32x32x16_bf16 C/D layout (HW-verified, learn_hip m74/m101):
//   col = lane&31, row = (reg&3) + 8*(reg>>2) + 4*(lane>>5)
// ---------------------------------------------------------------------------
__global__ __launch_bounds__(128, 2) void max_kernel(
        const __bf16* __restrict__ Apack, const __bf16* __restrict__ Ppack,
        const float* __restrict__ p_sq, float* __restrict__ partmax)
{
    const int tid  = threadIdx.x;               // 0..127
    const int wave = tid >> 6;                  // 0 or 1
    const int lane = tid & 63;
    const int l31  = lane & 31;
    const int half = lane >> 5;

    // XCD-locality swizzle: consecutive dispatch ids share a j-chunk mod 8
    const int bid = blockIdx.y * 64 + blockIdx.x;   // 0..1023
    const int jc  = bid & 15;                       // j-chunk
    const int ib  = bid >> 4;                       // i-block, 0..63

    const int i0    = ib * TI + wave * 64;          // wave's 64 anchor rows
    const int itile = i0 >> 5;
    const int jbase = jc * JCHUNK;
    const int tile0 = jbase >> 5;

    // A fragments (2 tiles), coalesced 1 KB wave-loads from Apack
    bf16x8 afA[8], afB[8];
    {
        const bf16x8* ap = (const bf16x8*)Apack;
        #pragma unroll
        for (int s = 0; s < 8; ++s) {
            afA[s] = ap[((size_t)itile * 8 + s) * 64 + lane];
            afB[s] = ap[((size_t)(itile + 1) * 8 + s) * 64 + lane];
        }
    }

    float rmaxA[16], rmaxB[16];
    #pragma unroll
    for (int r = 0; r < 16; ++r) { rmaxA[r] = -3.0e38f; rmaxB[r] = -3.0e38f; }

    // panel piece stream: panel p = pieces gp[p*512 + s*64], lane-offset
    const bf16x8* gp = (const bf16x8*)Ppack + (size_t)tile0 * 512 + lane;

    // register double buffer: prologue loads panel 0
    bf16x8 bcur[8], bnxt[8];
    #pragma unroll
    for (int s = 0; s < 8; ++s) bcur[s] = gp[s * 64];
    float cicur = -0.5f * p_sq[jbase + l31];
    float cinxt = 0.0f;

    #pragma unroll 2
    for (int t = 0; t < NP; ++t) {
        if (t + 1 < NP) {
            // prefetch panel t+1 into registers (stays in flight across
            // panel t's MFMAs; exact vmcnt tracking, no drain)
            #pragma unroll
            for (int s = 0; s < 8; ++s) bnxt[s] = gp[(t + 1) * 512 + s * 64];
            cinxt = -0.5f * p_sq[jbase + (t + 1) * 32 + l31];
        }

        f32x16 acc0, acc1;
        #pragma unroll
        for (int r = 0; r < 16; ++r) { acc0[r] = cicur; acc1[r] = cicur; }
        #pragma unroll
        for (int s = 0; s < 8; ++s) {
            acc0 = __builtin_amdgcn_mfma_f32_32x32x16_bf16(afA[s], bcur[s],
                                                           acc0, 0, 0, 0);
            acc1 = __builtin_amdgcn_mfma_f32_32x32x16_bf16(afB[s], bcur[s],
                                                           acc1, 0, 0, 0);
        }
        #pragma unroll
        for (int r = 0; r < 16; ++r) {
            rmaxA[r] = fmaxf(rmaxA[r], acc0[r]);
            rmaxB[r] = fmaxf(rmaxB[r], acc1[r]);
        }

        if (t + 1 < NP) {
            #pragma unroll
            for (int s = 0; s < 8; ++s) bcur[s] = bnxt[s];  // renamed away
            cicur = cinxt;
        }
    }

    // max across the 32 columns (lanes sharing the same half)
    #pragma unroll
    for (int r = 0; r < 16; ++r) {
        float vA = rmaxA[r], vB = rmaxB[r];
        #pragma unroll
        for (int off = 1; off <= 16; off <<= 1) {
            vA = fmaxf(vA, __shfl_xor(vA, off, 64));
            vB = fmaxf(vB, __shfl_xor(vB, off, 64));
        }
        rmaxA[r] = vA; rmaxB[r] = vB;
    }
    if (l31 == 0) {
        float* dst = partmax + (size_t)jc * BS + i0;
        #pragma unroll
        for (int r = 0; r < 16; ++r) {
            int row = (r & 3) + 8 * (r >> 2) + 4 * half;
            dst[row]      = rmaxA[r];
            dst[row + 32] = rmaxB[r];
        }
    }
}

// ---------------------------------------------------------------------------
// fused fin: 32 blocks x 256 threads; thread handles exactly one i.
// min_j d2 = a_sq[i] - 2 * max_c partmax[c][i]. Block sums go through a
// device-scope atomic accumulator; the last block (ticket 31) writes out.
// accum/cnt are zeroed by pack_kernel (stream-ordered).
// ---------------------------------------------------------------------------
__global__ __launch_bounds__(256) void fin_kernel(
        const float* __restrict__ partmax, const float* __restrict__ a_sq,
        const float* __restrict__ pd2, float* __restrict__ accum,
        unsigned int* __restrict__ cnt, float* __restrict__ out)
{
    __shared__ float ssum[4];
    const int t = threadIdx.x;
    const int i = blockIdx.x * 256 + t;

    float m = -3.0e38f;
    #pragma unroll
    for (int c = 0; c < NJC; ++c)
        m = fmaxf(m, partmax[c * BS + i]);
    float negd = sqrtf(fmaxf(fmaf(-2.0f, m, a_sq[i]), 0.0f));
    float posd = sqrtf(pd2[i]);
    float sum = fmaxf(posd - negd + 1.0f, 0.0f);

    #pragma unroll
    for (int off = 32; off >= 1; off >>= 1) sum += __shfl_xor(sum, off, 64);
    if ((t & 63) == 0) ssum[t >> 6] = sum;
    __syncthreads();
    if (t == 0) {
        float bs = ssum[0] + ssum[1] + ssum[2] + ssum[3];
        atomicAdd(accum, bs);
        __threadfence();
        unsigned int ticket = atomicAdd(cnt, 1u);
        if (ticket == 31u) {
            float total = atomicAdd(accum, 0.0f);   // device-scope read
            out[0] = total / (float)BS;
        }
    }
}

// ---------------------------------------------------------------------------
extern "C" void kernel_launch(void* const* d_in, const int* in_sizes, int n_in,
                              void* d_out, int out_size, void* d_ws,
                              size_t ws_size, hipStream_t stream)
{
    const float* feats = (const float*)d_in[0];

    char* ws = (char*)d_ws;
    __bf16* Apack = (__bf16*)ws;  ws += (size_t)BS * D * 2;   // 2 MB
    __bf16* Ppack = (__bf16*)ws;  ws += (size_t)BS * D * 2;   // 2 MB
    float* a_sq   = (float*)ws;   ws += (size_t)BS * 4;
    float* p_sq   = (float*)ws;   ws += (size_t)BS * 4;
    float* pd2    = (float*)ws;   ws += (size_t)BS * 4;
    float* partmax = (float*)ws;  ws += (size_t)NJC * BS * 4; // 512 KB
    float* accum  = (float*)ws;   ws += 64;
    unsigned int* cnt = (unsigned int*)ws; ws += 64;

    pack_kernel<<<BS / 32, 256, 0, stream>>>(feats, Apack, Ppack,
                                             a_sq, p_sq, pd2, accum, cnt);
    dim3 grid(64, NJC);
    max_kernel<<<grid, 128, 0, stream>>>(Apack, Ppack, p_sq, partmax);
    fin_kernel<<<BS / 256, 256, 0, stream>>>(partmax, a_sq, pd2,
                                             accum, cnt, (float*)d_out);
}